// Round 1
// 252.533 us; speedup vs baseline: 1.0000x; 1.0000x over previous
//
#include <hip/hip_runtime.h>
#include <hip/hip_bf16.h>

typedef unsigned short u16;
typedef unsigned int   u32;
typedef short   bf16x8 __attribute__((ext_vector_type(8)));  // bf16 carried as i16
typedef float   f32x4  __attribute__((ext_vector_type(4)));

__device__ __forceinline__ float bf2f(u16 u) {
    u32 t = ((u32)u) << 16;
    return __builtin_bit_cast(float, t);
}
__device__ __forceinline__ u32 f2bf(float f) {
    u32 u = __builtin_bit_cast(u32, f);
    return (u + 0x7FFFu + ((u >> 16) & 1u)) >> 16;   // RNE
}
// async global->LDS DMA, 16 B per lane (dst = wave-uniform base + lane*16)
__device__ __forceinline__ void load_lds16(const u16* g, u16* l) {
    __builtin_amdgcn_global_load_lds(
        (const __attribute__((address_space(1))) u32*)(const void*)g,
        (__attribute__((address_space(3))) u32*)(void*)l, 16, 0, 0);
}

// ---------------------------------------------------------------------------
// GLOBAL K-ORDER (both GEMMs): r = t*256 + c  (tap-major).
// ---------------------------------------------------------------------------

// Kernel 0a: offset/mask conv weights -> hi/lo bf16 A[32][2304], r = t*256+c
__global__ void kprep(const float* __restrict__ woff, const float* __restrict__ wmod,
                      u16* __restrict__ ah, u16* __restrict__ al) {
    int i = blockIdx.x * 256 + threadIdx.x;      // 288 blocks -> 73728 exact
    if (i >= 32 * 2304) return;
    int oc = i / 2304, r = i - oc * 2304;
    int t = r >> 8, c = r & 255;
    float v = 0.f;
    if (oc < 18)      v = woff[oc * 2304 + c * 9 + t];
    else if (oc < 27) v = wmod[(oc - 18) * 2304 + c * 9 + t];
    u32 hb = f2bf(v);
    u32 lb = f2bf(v - bf2f((u16)hb));
    ah[i] = (u16)hb;
    al[i] = (u16)lb;
}

// Kernel 0b: w_reg f32 -> bf16, layout [o][t*256+c] (matches gather K-order).
__global__ void kwreg(const float* __restrict__ wreg, u16* __restrict__ wregb) {
    int i = blockIdx.x * 256 + threadIdx.x;      // 2304 blocks exact
    int o = i / 2304, r = i - o * 2304;
    int t = r >> 8, c = r & 255;
    wregb[i] = (u16)f2bf(wreg[o * 2304 + c * 9 + t]);
}

// ---------------------------------------------------------------------------
// Kernel 1: offset/mask conv as MFMA GEMM, M=32 (27 live), N=16384, K=2304.
// hi/lo bf16 split on both operands -> 3 MFMAs, fp32-equivalent precision.
// Fused bias + 2*sigmoid epilogue writes offf directly.
// ---------------------------------------------------------------------------
__global__ __launch_bounds__(256) void koffg(const float* __restrict__ x,
                                             const u16* __restrict__ ah_g,
                                             const u16* __restrict__ al_g,
                                             const float* __restrict__ boff,
                                             const float* __restrict__ bmod,
                                             float* __restrict__ offf) {
    __shared__ u16 Ah[32 * 72], Al[32 * 72];     // 32 oc-rows, 64 k + 8 pad
    __shared__ u16 Bh[32 * 72], Bl[32 * 72];     // 32 n-rows,  64 k + 8 pad
    int tid = threadIdx.x;
    int n0 = blockIdx.x * 32;
    int b = n0 >> 12, h0 = (n0 & 4095) >> 6, w0 = n0 & 63;
    int lane = tid & 63, wv = tid >> 6;
    int mt = wv & 1, nt = wv >> 1;               // 2 m-tiles x 2 n-tiles of 16
    int col = lane & 15, quad = lane >> 4;

    int aoc = tid >> 3, ak0 = (tid & 7) * 8;     // A staging role
    int nl = tid & 31, cl0 = (tid >> 5) * 8;     // B staging role

    f32x4 acc = (f32x4){0.f, 0.f, 0.f, 0.f};

    for (int kt = 0; kt < 36; kt++) {
        int t = kt >> 2, c0 = (kt & 3) << 6;
        int r0 = kt * 64;
        int dy = t / 3 - 1, dx = t % 3 - 1;
        uint4 pah = *(const uint4*)(ah_g + aoc * 2304 + r0 + ak0);
        uint4 pal = *(const uint4*)(al_g + aoc * 2304 + r0 + ak0);
        int hp = h0 + dy, wp = w0 + nl + dx;
        bool vm = ((unsigned)hp < 64u) && ((unsigned)wp < 64u);
        int hc = min(max(hp, 0), 63), wc = min(max(wp, 0), 63);
        const float* xp = x + ((long)(b * 256 + c0 + cl0) << 12) + hc * 64 + wc;
        u32 whi[4], wlo[4];
#pragma unroll
        for (int i = 0; i < 8; i++) {
            float v = vm ? xp[(long)i << 12] : 0.f;
            u32 hb = f2bf(v);
            u32 lb = f2bf(v - bf2f((u16)hb));
            if (i & 1) { whi[i >> 1] |= hb << 16; wlo[i >> 1] |= lb << 16; }
            else       { whi[i >> 1]  = hb;       wlo[i >> 1]  = lb; }
        }
        __syncthreads();
        *(uint4*)&Ah[aoc * 72 + ak0] = pah;
        *(uint4*)&Al[aoc * 72 + ak0] = pal;
        *(uint4*)&Bh[nl * 72 + cl0] = make_uint4(whi[0], whi[1], whi[2], whi[3]);
        *(uint4*)&Bl[nl * 72 + cl0] = make_uint4(wlo[0], wlo[1], wlo[2], wlo[3]);
        __syncthreads();
#pragma unroll
        for (int ks = 0; ks < 2; ks++) {
            int ko = ks * 32 + quad * 8;
            bf16x8 fah = *(const bf16x8*)&Ah[(mt * 16 + col) * 72 + ko];
            bf16x8 fal = *(const bf16x8*)&Al[(mt * 16 + col) * 72 + ko];
            bf16x8 fbh = *(const bf16x8*)&Bh[(nt * 16 + col) * 72 + ko];
            bf16x8 fbl = *(const bf16x8*)&Bl[(nt * 16 + col) * 72 + ko];
            acc = __builtin_amdgcn_mfma_f32_16x16x32_bf16(fah, fbh, acc, 0, 0, 0);
            acc = __builtin_amdgcn_mfma_f32_16x16x32_bf16(fah, fbl, acc, 0, 0, 0);
            acc = __builtin_amdgcn_mfma_f32_16x16x32_bf16(fal, fbh, acc, 0, 0, 0);
        }
    }

    int n = n0 + nt * 16 + col;
#pragma unroll
    for (int r = 0; r < 4; r++) {
        int oc = mt * 16 + quad * 4 + r;
        float s = acc[r];
        if (oc < 18) {
            int ch = 3 * (oc >> 1) + (oc & 1);   // even oc -> dy, odd -> dx
            offf[(ch << 14) + n] = s + boff[oc];
        } else if (oc < 27) {
            float tt = s + bmod[oc - 18];
            int ch = 3 * (oc - 18) + 2;
            offf[(ch << 14) + n] = 2.f / (1.f + __expf(-tt));
        }
    }
}

// ---------------------------------------------------------------------------
// Kernel 2 (FUSED): deformable bilinear sampling + GEMM + BN + ReLU.
// Block = 64 pixels (one h-row of one image) x 256 outputs, 512 thr, 8 waves.
// K streams in r = t*256+c order, BK=64 (one tap, one 64-channel chunk).
// Per K-step each thread gathers its pixel's 8-channel octet straight into
// registers (bilinear, mask folded into weights), packs bf16, ds_writes the
// proven Bl[8][64][8] layout; A streams via swizzled global_load_lds.
// The samp HBM round trip is gone; gather latency overlaps the MFMA phase.
// Tap state (indices + 4 weights) is computed once per tap (every 4 kt).
// b,h are wave-uniform by construction (derived from blockIdx.x only) so
// gather bases stay in SGPRs -> 1 VGPR voffset per neighbor.
// ---------------------------------------------------------------------------
__global__ __launch_bounds__(512, 2) void kfused(const float* __restrict__ x,
                                                 const float* __restrict__ offf,
                                                 const u16* __restrict__ wregb,
                                                 const float* __restrict__ gamma,
                                                 const float* __restrict__ beta,
                                                 const float* __restrict__ rmean,
                                                 const float* __restrict__ rvar,
                                                 float* __restrict__ out) {
    __shared__ u16 Al[256 * 64];     // [o][k] granule-XOR-swizzled, 32 KB
    __shared__ u16 Bl[8 * 64 * 8];   // [c-octet][n][8ch], 8 KB
    int tid = threadIdx.x;
    int lane = tid & 63, wv = tid >> 6;
    int nl = lane, og = wv;                      // pixel-in-block, channel octet
    int bb = blockIdx.x >> 6;                    // image   (block-uniform)
    int h  = blockIdx.x & 63;                    // row     (block-uniform)
    int n  = blockIdx.x * 64 + nl;               // global pixel id
    int wo = (wv >> 1) * 64, wn = (wv & 1) * 32; // wave output tile 64o x 32n
    int col = lane & 15, quad = lane >> 4;

    const float* xg = x + ((long)(bb * 256 + og * 8) << 12);  // + (c0+cc)<<12

    f32x4 acc[4][2];
#pragma unroll
    for (int i = 0; i < 4; i++)
#pragma unroll
        for (int j = 0; j < 2; j++) acc[i][j] = (f32x4){0.f, 0.f, 0.f, 0.f};

    int   o00 = 0, o01 = 0, o10 = 0, o11 = 0;
    float s00 = 0.f, s01 = 0.f, s10 = 0.f, s11 = 0.f;

    for (int kt = 0; kt < 36; kt++) {
        int r0 = kt * 64, c0 = (kt & 3) << 6;

        // A staging: 2048 x 16B granules, async DMA (overlaps the gathers)
#pragma unroll
        for (int i = 0; i < 4; i++) {
            int cidx = tid + i * 512;
            int o = cidx >> 3, qp = cidx & 7;
            int ql = qp ^ (o & 7);               // source-side XOR swizzle
            load_lds16(wregb + (long)o * 2304 + r0 + ql * 8, &Al[cidx * 8]);
        }

        if ((kt & 3) == 0) {                     // new tap: rebuild gather state
            int t = kt >> 2;
            int g = t / 3, tx = t - 3 * g;
            float dy = offf[((3 * t + 0) << 14) + n];
            float dx = offf[((3 * t + 1) << 14) + n];
            float m  = offf[((3 * t + 2) << 14) + n];
            float py = (float)(h - 1 + g) + dy;
            float px = (float)(nl - 1 + tx) + dx;
            float y0f = floorf(py), x0f = floorf(px);
            float wy = py - y0f, wx = px - x0f;
            int iy0 = (int)y0f, ix0 = (int)x0f;
            int iy1 = iy0 + 1, ix1 = ix0 + 1;
            bool vy0 = (unsigned)iy0 < 64u, vy1 = (unsigned)iy1 < 64u;
            bool vx0 = (unsigned)ix0 < 64u, vx1 = (unsigned)ix1 < 64u;
            int cy0 = min(max(iy0, 0), 63), cy1 = min(max(iy1, 0), 63);
            int cx0 = min(max(ix0, 0), 63), cx1 = min(max(ix1, 0), 63);
            o00 = cy0 * 64 + cx0; o01 = cy0 * 64 + cx1;
            o10 = cy1 * 64 + cx0; o11 = cy1 * 64 + cx1;
            float a = 1.f - wy, bw = 1.f - wx;
            s00 = (vy0 && vx0) ? a  * bw * m : 0.f;
            s01 = (vy0 && vx1) ? a  * wx * m : 0.f;
            s10 = (vy1 && vx0) ? wy * bw * m : 0.f;
            s11 = (vy1 && vx1) ? wy * wx * m : 0.f;
        }

        // bilinear gather: 8 channels x 4 neighbors -> bf16-packed uint4
        u32 wd[4];
#pragma unroll
        for (int cc = 0; cc < 8; cc++) {
            const float* xp = xg + ((long)(c0 + cc) << 12);
            float v = s00 * xp[o00] + s01 * xp[o01] +
                      s10 * xp[o10] + s11 * xp[o11];
            u32 bv = f2bf(v);
            if (cc & 1) wd[cc >> 1] |= bv << 16;
            else        wd[cc >> 1]  = bv;
        }

        // staging writes land after prev iteration's closing barrier
        *(uint4*)&Bl[(og * 64 + nl) * 8] = make_uint4(wd[0], wd[1], wd[2], wd[3]);
        __syncthreads();                         // drains DMA (vmcnt) + ds_write

#pragma unroll
        for (int ks = 0; ks < 2; ks++) {
            bf16x8 af[4], bfr[2];
#pragma unroll
            for (int i = 0; i < 4; i++) {
                int r = wo + i * 16 + col;
                int ph = (ks * 4 + quad) ^ (r & 7);
                af[i] = *(const bf16x8*)&Al[r * 64 + ph * 8];
            }
#pragma unroll
            for (int j = 0; j < 2; j++)
                bfr[j] = *(const bf16x8*)&Bl[((ks * 4 + quad) * 64 +
                                              (wn + j * 16 + col)) * 8];
#pragma unroll
            for (int i = 0; i < 4; i++)
#pragma unroll
                for (int j = 0; j < 2; j++)
                    acc[i][j] = __builtin_amdgcn_mfma_f32_16x16x32_bf16(
                        af[i], bfr[j], acc[i][j], 0, 0, 0);
        }
        __syncthreads();                         // frag reads done before next stage
    }

    // epilogue: BN + ReLU, D layout: row(o) = quad*4+reg, col(n) = lane&15
#pragma unroll
    for (int i = 0; i < 4; i++) {
        int ob = wo + i * 16 + quad * 4;
        float inv[4], add[4];
#pragma unroll
        for (int r = 0; r < 4; r++) {
            int o = ob + r;
            float iv = gamma[o] * rsqrtf(rvar[o] + 1e-5f);
            inv[r] = iv; add[r] = beta[o] - rmean[o] * iv;
        }
#pragma unroll
        for (int j = 0; j < 2; j++) {
            int n_g = blockIdx.x * 64 + wn + j * 16 + col;
            int bq = n_g >> 12, hw = n_g & 4095;
            float* op = out + ((long)bq << 20) + hw;
#pragma unroll
            for (int r = 0; r < 4; r++) {
                float v = acc[i][j][r] * inv[r] + add[r];
                v = fmaxf(v, 0.f);
                op[(long)(ob + r) << 12] = v;
            }
        }
    }
}

// ---------------------------------------------------------------------------
extern "C" void kernel_launch(void* const* d_in, const int* in_sizes, int n_in,
                              void* d_out, int out_size, void* d_ws, size_t ws_size,
                              hipStream_t stream) {
    const float* x     = (const float*)d_in[0];
    const float* woff  = (const float*)d_in[1];
    const float* boff  = (const float*)d_in[2];
    const float* wmod  = (const float*)d_in[3];
    const float* bmod  = (const float*)d_in[4];
    const float* wreg  = (const float*)d_in[5];
    const float* gamma = (const float*)d_in[6];
    const float* beta  = (const float*)d_in[7];
    const float* rmean = (const float*)d_in[8];
    const float* rvar  = (const float*)d_in[9];
    float* out = (float*)d_out;

    char* ws = (char*)d_ws;
    // ws map:
    //   [0x000000, 0x024000) wph   bf16  144 KB (A hi, koffg)
    //   [0x040000, 0x064000) wpl   bf16  144 KB (A lo)
    //   [0x080000, 0x23C000) offf  fp32  1.77 MB
    //   [0x240000, 0x360000) wregb bf16  1.18 MB ([o][t*256+c] order)
    u16*   wph   = (u16*)(ws);
    u16*   wpl   = (u16*)(ws + 0x40000u);
    float* offf  = (float*)(ws + 0x80000u);
    u16*   wregb = (u16*)(ws + 0x240000u);

    kprep<<<288,  256, 0, stream>>>(woff, wmod, wph, wpl);
    kwreg<<<2304, 256, 0, stream>>>(wreg, wregb);
    koffg<<<512,  256, 0, stream>>>(x, wph, wpl, boff, bmod, offf);
    kfused<<<256, 512, 0, stream>>>(x, offf, wregb, gamma, beta,
                                    rmean, rvar, out);
}

// Round 2
// 242.228 us; speedup vs baseline: 1.0425x; 1.0425x over previous
//
#include <hip/hip_runtime.h>
#include <hip/hip_bf16.h>

typedef unsigned short u16;
typedef unsigned int   u32;
typedef short   bf16x8 __attribute__((ext_vector_type(8)));  // bf16 carried as i16
typedef float   f32x4  __attribute__((ext_vector_type(4)));

__device__ __forceinline__ float bf2f(u16 u) {
    u32 t = ((u32)u) << 16;
    return __builtin_bit_cast(float, t);
}
__device__ __forceinline__ u32 f2bf(float f) {
    u32 u = __builtin_bit_cast(u32, f);
    return (u + 0x7FFFu + ((u >> 16) & 1u)) >> 16;   // RNE
}
// async global->LDS DMA, 16 B per lane (dst = wave-uniform base + lane*16)
__device__ __forceinline__ void load_lds16(const u16* g, u16* l) {
    __builtin_amdgcn_global_load_lds(
        (const __attribute__((address_space(1))) u32*)(const void*)g,
        (__attribute__((address_space(3))) u32*)(void*)l, 16, 0, 0);
}

// ---------------------------------------------------------------------------
// GLOBAL K-ORDER (both GEMMs): r = t*256 + c  (tap-major).
// ---------------------------------------------------------------------------

// Kernel 0a: offset/mask conv weights -> hi/lo bf16 A[32][2304], r = t*256+c
__global__ void kprep(const float* __restrict__ woff, const float* __restrict__ wmod,
                      u16* __restrict__ ah, u16* __restrict__ al) {
    int i = blockIdx.x * 256 + threadIdx.x;      // 288 blocks -> 73728 exact
    if (i >= 32 * 2304) return;
    int oc = i / 2304, r = i - oc * 2304;
    int t = r >> 8, c = r & 255;
    float v = 0.f;
    if (oc < 18)      v = woff[oc * 2304 + c * 9 + t];
    else if (oc < 27) v = wmod[(oc - 18) * 2304 + c * 9 + t];
    u32 hb = f2bf(v);
    u32 lb = f2bf(v - bf2f((u16)hb));
    ah[i] = (u16)hb;
    al[i] = (u16)lb;
}

// Kernel 0b: w_reg f32 -> bf16, layout [o][t*256+c] (matches gather K-order).
__global__ void kwreg(const float* __restrict__ wreg, u16* __restrict__ wregb) {
    int i = blockIdx.x * 256 + threadIdx.x;      // 2304 blocks exact
    int o = i / 2304, r = i - o * 2304;
    int t = r >> 8, c = r & 255;
    wregb[i] = (u16)f2bf(wreg[o * 2304 + c * 9 + t]);
}

// ---------------------------------------------------------------------------
// Kernel 1: offset/mask conv as MFMA GEMM, M=32 (27 live), N=16384, K=2304.
// hi/lo bf16 split on both operands -> 3 MFMAs, fp32-equivalent precision.
// PIPELINED: double-buffered LDS, prefetch loads for kt+1 before MFMA(kt),
// convert+LDS-write after MFMA, ONE barrier per kt (was two).
// ---------------------------------------------------------------------------
__global__ __launch_bounds__(256) void koffg(const float* __restrict__ x,
                                             const u16* __restrict__ ah_g,
                                             const u16* __restrict__ al_g,
                                             const float* __restrict__ boff,
                                             const float* __restrict__ bmod,
                                             float* __restrict__ offf) {
    __shared__ u16 Ah[2][32 * 72], Al[2][32 * 72]; // 32 oc-rows, 64 k + 8 pad
    __shared__ u16 Bh[2][32 * 72], Bl[2][32 * 72]; // 32 n-rows,  64 k + 8 pad
    int tid = threadIdx.x;
    int n0 = blockIdx.x * 32;
    int b = n0 >> 12, h0 = (n0 & 4095) >> 6, w0 = n0 & 63;
    int lane = tid & 63, wv = tid >> 6;
    int mt = wv & 1, nt = wv >> 1;               // 2 m-tiles x 2 n-tiles of 16
    int col = lane & 15, quad = lane >> 4;

    int aoc = tid >> 3, ak0 = (tid & 7) * 8;     // A staging role
    int nl = tid & 31, cl0 = (tid >> 5) * 8;     // B staging role

    f32x4 acc = (f32x4){0.f, 0.f, 0.f, 0.f};

    uint4 pah, pal;
    float xv[8];

    auto loads = [&](int kt) {
        int t = kt >> 2, c0 = (kt & 3) << 6, r0 = kt * 64;
        int dy = t / 3 - 1, dx = t % 3 - 1;
        pah = *(const uint4*)(ah_g + aoc * 2304 + r0 + ak0);
        pal = *(const uint4*)(al_g + aoc * 2304 + r0 + ak0);
        int hp = h0 + dy, wp = w0 + nl + dx;
        bool vm = ((unsigned)hp < 64u) && ((unsigned)wp < 64u);
        int hc = min(max(hp, 0), 63), wc = min(max(wp, 0), 63);
        const float* xp = x + ((long)(b * 256 + c0 + cl0) << 12) + hc * 64 + wc;
#pragma unroll
        for (int i = 0; i < 8; i++) xv[i] = vm ? xp[(long)i << 12] : 0.f;
    };
    auto stores = [&](int buf) {
        u32 whi[4], wlo[4];
#pragma unroll
        for (int i = 0; i < 8; i++) {
            u32 hb = f2bf(xv[i]);
            u32 lb = f2bf(xv[i] - bf2f((u16)hb));
            if (i & 1) { whi[i >> 1] |= hb << 16; wlo[i >> 1] |= lb << 16; }
            else       { whi[i >> 1]  = hb;       wlo[i >> 1]  = lb; }
        }
        *(uint4*)&Ah[buf][aoc * 72 + ak0] = pah;
        *(uint4*)&Al[buf][aoc * 72 + ak0] = pal;
        *(uint4*)&Bh[buf][nl * 72 + cl0] = make_uint4(whi[0], whi[1], whi[2], whi[3]);
        *(uint4*)&Bl[buf][nl * 72 + cl0] = make_uint4(wlo[0], wlo[1], wlo[2], wlo[3]);
    };

    loads(0);
    stores(0);
    __syncthreads();

    for (int kt = 0; kt < 36; kt++) {
        int cur = kt & 1, nxt = kt + 1;
        if (nxt < 36) loads(nxt);                // in flight over MFMA phase
#pragma unroll
        for (int ks = 0; ks < 2; ks++) {
            int ko = ks * 32 + quad * 8;
            bf16x8 fah = *(const bf16x8*)&Ah[cur][(mt * 16 + col) * 72 + ko];
            bf16x8 fal = *(const bf16x8*)&Al[cur][(mt * 16 + col) * 72 + ko];
            bf16x8 fbh = *(const bf16x8*)&Bh[cur][(nt * 16 + col) * 72 + ko];
            bf16x8 fbl = *(const bf16x8*)&Bl[cur][(nt * 16 + col) * 72 + ko];
            acc = __builtin_amdgcn_mfma_f32_16x16x32_bf16(fah, fbh, acc, 0, 0, 0);
            acc = __builtin_amdgcn_mfma_f32_16x16x32_bf16(fah, fbl, acc, 0, 0, 0);
            acc = __builtin_amdgcn_mfma_f32_16x16x32_bf16(fal, fbh, acc, 0, 0, 0);
        }
        if (nxt < 36) stores(nxt & 1);           // convert + write late
        __syncthreads();                         // one barrier per kt
    }

    int n = n0 + nt * 16 + col;
#pragma unroll
    for (int r = 0; r < 4; r++) {
        int oc = mt * 16 + quad * 4 + r;
        float s = acc[r];
        if (oc < 18) {
            int ch = 3 * (oc >> 1) + (oc & 1);   // even oc -> dy, odd -> dx
            offf[(ch << 14) + n] = s + boff[oc];
        } else if (oc < 27) {
            float tt = s + bmod[oc - 18];
            int ch = 3 * (oc - 18) + 2;
            offf[(ch << 14) + n] = 2.f / (1.f + __expf(-tt));
        }
    }
}

// ---------------------------------------------------------------------------
// Kernel 2 (FUSED, PIPELINED): deformable sampling + GEMM + BN + ReLU.
// Block = 64 pixels x 256 outputs, 512 thr, 8 waves, grid 256 (1 block/CU).
// Per kt: issue gathers(kt+1) + A-DMA(kt+1) -> MFMA(kt) (hides the gather
// latency) -> weight/pack/ds_write Bl(kt+1) -> ONE barrier. LDS double-
// buffered (Wl 64 KB + Sl 16 KB). In-flight gather state: 32 floats.
// ---------------------------------------------------------------------------
__global__ __launch_bounds__(512, 2) void kfused(const float* __restrict__ x,
                                                 const float* __restrict__ offf,
                                                 const u16* __restrict__ wregb,
                                                 const float* __restrict__ gamma,
                                                 const float* __restrict__ beta,
                                                 const float* __restrict__ rmean,
                                                 const float* __restrict__ rvar,
                                                 float* __restrict__ out) {
    __shared__ u16 Wl[2][256 * 64];  // [buf][o][k] granule-XOR-swizzled, 64 KB
    __shared__ u16 Sl[2][8 * 64 * 8];// [buf][c-octet][n][8ch], 16 KB
    int tid = threadIdx.x;
    int lane = tid & 63, wv = tid >> 6;
    int nl = lane, og = wv;                      // pixel-in-block, channel octet
    int bb = blockIdx.x >> 6;                    // image   (block-uniform)
    int h  = blockIdx.x & 63;                    // row     (block-uniform)
    int n  = blockIdx.x * 64 + nl;               // global pixel id
    int wo = (wv >> 1) * 64, wn = (wv & 1) * 32; // wave output tile 64o x 32n
    int col = lane & 15, quad = lane >> 4;

    const float* xg = x + ((long)(bb * 256 + og * 8) << 12);  // + (c0+cc)<<12

    f32x4 acc[4][2];
#pragma unroll
    for (int i = 0; i < 4; i++)
#pragma unroll
        for (int j = 0; j < 2; j++) acc[i][j] = (f32x4){0.f, 0.f, 0.f, 0.f};

    int   o00 = 0, o01 = 0, o10 = 0, o11 = 0;
    float s00 = 0.f, s01 = 0.f, s10 = 0.f, s11 = 0.f;
    float g00[8], g01[8], g10[8], g11[8];        // in-flight gather values

    auto tapst = [&](int t) {                    // rebuild tap state (every 4 kt)
        int g = t / 3, tx = t - 3 * g;
        float dy = offf[((3 * t + 0) << 14) + n];
        float dx = offf[((3 * t + 1) << 14) + n];
        float m  = offf[((3 * t + 2) << 14) + n];
        float py = (float)(h - 1 + g) + dy;
        float px = (float)(nl - 1 + tx) + dx;
        float y0f = floorf(py), x0f = floorf(px);
        float wy = py - y0f, wx = px - x0f;
        int iy0 = (int)y0f, ix0 = (int)x0f;
        int iy1 = iy0 + 1, ix1 = ix0 + 1;
        bool vy0 = (unsigned)iy0 < 64u, vy1 = (unsigned)iy1 < 64u;
        bool vx0 = (unsigned)ix0 < 64u, vx1 = (unsigned)ix1 < 64u;
        int cy0 = min(max(iy0, 0), 63), cy1 = min(max(iy1, 0), 63);
        int cx0 = min(max(ix0, 0), 63), cx1 = min(max(ix1, 0), 63);
        o00 = cy0 * 64 + cx0; o01 = cy0 * 64 + cx1;
        o10 = cy1 * 64 + cx0; o11 = cy1 * 64 + cx1;
        float a = 1.f - wy, bw = 1.f - wx;
        s00 = (vy0 && vx0) ? a  * bw * m : 0.f;
        s01 = (vy0 && vx1) ? a  * wx * m : 0.f;
        s10 = (vy1 && vx0) ? wy * bw * m : 0.f;
        s11 = (vy1 && vx1) ? wy * wx * m : 0.f;
    };
    auto gissue = [&](int kt) {                  // issue 32 gather loads
        int c0 = (kt & 3) << 6;
#pragma unroll
        for (int cc = 0; cc < 8; cc++) {
            const float* xp = xg + ((long)(c0 + cc) << 12);
            g00[cc] = xp[o00]; g01[cc] = xp[o01];
            g10[cc] = xp[o10]; g11[cc] = xp[o11];
        }
    };
    auto dmaA = [&](int kt, int buf) {           // async A staging, 32 KB
#pragma unroll
        for (int i = 0; i < 4; i++) {
            int cidx = tid + i * 512;
            int o = cidx >> 3, qp = cidx & 7;
            int ql = qp ^ (o & 7);               // source-side XOR swizzle
            load_lds16(wregb + (long)o * 2304 + kt * 64 + ql * 8,
                       &Wl[buf][cidx * 8]);
        }
    };
    auto bwrite = [&](int buf) {                 // weight + pack + ds_write
        u32 wd[4];
#pragma unroll
        for (int cc = 0; cc < 8; cc++) {
            float v = s00 * g00[cc] + s01 * g01[cc] +
                      s10 * g10[cc] + s11 * g11[cc];
            u32 bv = f2bf(v);
            if (cc & 1) wd[cc >> 1] |= bv << 16;
            else        wd[cc >> 1]  = bv;
        }
        *(uint4*)&Sl[buf][(og * 64 + nl) * 8] =
            make_uint4(wd[0], wd[1], wd[2], wd[3]);
    };

    // prologue: fill buffer 0
    tapst(0);
    gissue(0);
    dmaA(0, 0);
    bwrite(0);
    __syncthreads();

    for (int kt = 0; kt < 36; kt++) {
        int cur = kt & 1, nxt = kt + 1;
        if (nxt < 36) {
            if ((nxt & 3) == 0) tapst(nxt >> 2);
            gissue(nxt);                         // latency hides under MFMA
            dmaA(nxt, nxt & 1);
        }
#pragma unroll
        for (int ks = 0; ks < 2; ks++) {
            bf16x8 af[4], bfr[2];
#pragma unroll
            for (int i = 0; i < 4; i++) {
                int r = wo + i * 16 + col;
                int ph = (ks * 4 + quad) ^ (r & 7);
                af[i] = *(const bf16x8*)&Wl[cur][r * 64 + ph * 8];
            }
#pragma unroll
            for (int j = 0; j < 2; j++)
                bfr[j] = *(const bf16x8*)&Sl[cur][((ks * 4 + quad) * 64 +
                                                   (wn + j * 16 + col)) * 8];
#pragma unroll
            for (int i = 0; i < 4; i++)
#pragma unroll
                for (int j = 0; j < 2; j++)
                    acc[i][j] = __builtin_amdgcn_mfma_f32_16x16x32_bf16(
                        af[i], bfr[j], acc[i][j], 0, 0, 0);
        }
        if (nxt < 36) bwrite(nxt & 1);           // write late (after MFMA)
        __syncthreads();                         // drains DMA + ds_write; one/kt
    }

    // epilogue: BN + ReLU, D layout: row(o) = quad*4+reg, col(n) = lane&15
#pragma unroll
    for (int i = 0; i < 4; i++) {
        int ob = wo + i * 16 + quad * 4;
        float inv[4], add[4];
#pragma unroll
        for (int r = 0; r < 4; r++) {
            int o = ob + r;
            float iv = gamma[o] * rsqrtf(rvar[o] + 1e-5f);
            inv[r] = iv; add[r] = beta[o] - rmean[o] * iv;
        }
#pragma unroll
        for (int j = 0; j < 2; j++) {
            int n_g = blockIdx.x * 64 + wn + j * 16 + col;
            int bq = n_g >> 12, hw = n_g & 4095;
            float* op = out + ((long)bq << 20) + hw;
#pragma unroll
            for (int r = 0; r < 4; r++) {
                float v = acc[i][j][r] * inv[r] + add[r];
                v = fmaxf(v, 0.f);
                op[(long)(ob + r) << 12] = v;
            }
        }
    }
}

// ---------------------------------------------------------------------------
extern "C" void kernel_launch(void* const* d_in, const int* in_sizes, int n_in,
                              void* d_out, int out_size, void* d_ws, size_t ws_size,
                              hipStream_t stream) {
    const float* x     = (const float*)d_in[0];
    const float* woff  = (const float*)d_in[1];
    const float* boff  = (const float*)d_in[2];
    const float* wmod  = (const float*)d_in[3];
    const float* bmod  = (const float*)d_in[4];
    const float* wreg  = (const float*)d_in[5];
    const float* gamma = (const float*)d_in[6];
    const float* beta  = (const float*)d_in[7];
    const float* rmean = (const float*)d_in[8];
    const float* rvar  = (const float*)d_in[9];
    float* out = (float*)d_out;

    char* ws = (char*)d_ws;
    // ws map:
    //   [0x000000, 0x024000) wph   bf16  144 KB (A hi, koffg)
    //   [0x040000, 0x064000) wpl   bf16  144 KB (A lo)
    //   [0x080000, 0x23C000) offf  fp32  1.77 MB
    //   [0x240000, 0x360000) wregb bf16  1.18 MB ([o][t*256+c] order)
    u16*   wph   = (u16*)(ws);
    u16*   wpl   = (u16*)(ws + 0x40000u);
    float* offf  = (float*)(ws + 0x80000u);
    u16*   wregb = (u16*)(ws + 0x240000u);

    kprep<<<288,  256, 0, stream>>>(woff, wmod, wph, wpl);
    kwreg<<<2304, 256, 0, stream>>>(wreg, wregb);
    koffg<<<512,  256, 0, stream>>>(x, wph, wpl, boff, bmod, offf);
    kfused<<<256, 512, 0, stream>>>(x, offf, wregb, gamma, beta,
                                    rmean, rvar, out);
}